// Round 3
// baseline (805.159 us; speedup 1.0000x reference)
//
#include <hip/hip_runtime.h>
#include <cstddef>
#include <cstdint>

#define B_ 16
#define H_ 16
#define NQ 8
#define D_ 128
#define E_ 2048
#define F3 6144
#define KVP 4096
#define KVT 4104
#define SCALE 0.08838834764831843f
#define NCHUNK 8
#define CHUNK 512
#define SUBR 32
#define NSUB 16
#define PARTSZ 1040  // 8 m + 8 l + 8*128 acc

// LDS-only barrier: order LDS ops, let global stores stay in flight (no vmcnt drain).
#define LBAR()                                         \
  do {                                                 \
    asm volatile("s_waitcnt lgkmcnt(0)" ::: "memory"); \
    __builtin_amdgcn_s_barrier();                      \
    __builtin_amdgcn_sched_barrier(0);                 \
  } while (0)

// ---------------- GEMM: C[M][F] = X[M][K] * W[F][K]^T (fp32) ----------------
template <int BM, int BN>
__global__ __launch_bounds__(256) void gemm_xwt(const float* __restrict__ X,
                                                const float* __restrict__ W,
                                                float* __restrict__ C,
                                                int K, int Fdim) {
  constexpr int BK = 32;
  constexpr int RM = BM / 16;
  constexpr int RN = BN / 16;
  __shared__ float xs[BK][BM + 4];
  __shared__ float wss[BK][BN + 4];
  const int t = threadIdx.x;
  const int tm = t >> 4, tn = t & 15;
  const int m0 = blockIdx.y * BM, f0 = blockIdx.x * BN;
  float acc[RM][RN];
#pragma unroll
  for (int i = 0; i < RM; ++i)
#pragma unroll
    for (int j = 0; j < RN; ++j) acc[i][j] = 0.f;

  for (int kk = 0; kk < K; kk += BK) {
#pragma unroll
    for (int i = 0; i < (BM * BK) / 1024; ++i) {
      int j = t + i * 256;
      int r = j >> 3;
      int c = (j & 7) << 2;
      float4 v = *reinterpret_cast<const float4*>(&X[(size_t)(m0 + r) * K + kk + c]);
      xs[c + 0][r] = v.x; xs[c + 1][r] = v.y; xs[c + 2][r] = v.z; xs[c + 3][r] = v.w;
    }
#pragma unroll
    for (int i = 0; i < (BN * BK) / 1024; ++i) {
      int j = t + i * 256;
      int r = j >> 3;
      int c = (j & 7) << 2;
      float4 v = *reinterpret_cast<const float4*>(&W[(size_t)(f0 + r) * K + kk + c]);
      wss[c + 0][r] = v.x; wss[c + 1][r] = v.y; wss[c + 2][r] = v.z; wss[c + 3][r] = v.w;
    }
    __syncthreads();
#pragma unroll
    for (int k = 0; k < BK; ++k) {
      float xv[RM], wv[RN];
      if constexpr (RM == 4) {
        *reinterpret_cast<float4*>(xv) = *reinterpret_cast<const float4*>(&xs[k][tm * 4]);
      } else {
        *reinterpret_cast<float2*>(xv) = *reinterpret_cast<const float2*>(&xs[k][tm * 2]);
      }
      if constexpr (RN == 4) {
        *reinterpret_cast<float4*>(wv) = *reinterpret_cast<const float4*>(&wss[k][tn * 4]);
      } else {
        *reinterpret_cast<float2*>(wv) = *reinterpret_cast<const float2*>(&wss[k][tn * 2]);
      }
#pragma unroll
      for (int i = 0; i < RM; ++i)
#pragma unroll
        for (int j = 0; j < RN; ++j) acc[i][j] += xv[i] * wv[j];
    }
    __syncthreads();
  }
#pragma unroll
  for (int i = 0; i < RM; ++i) {
    float* cp = &C[(size_t)(m0 + tm * RM + i) * Fdim + f0 + tn * RN];
    if constexpr (RN == 4) {
      *reinterpret_cast<float4*>(cp) = make_float4(acc[i][0], acc[i][1], acc[i][2], acc[i][3]);
    } else {
      *reinterpret_cast<float2*>(cp) = make_float2(acc[i][0], acc[i][1]);
    }
  }
}

// ------- Fused KV-cache copy + flash-attention partials over past chunks -------
// grid: (NCHUNK, H, B), 256 threads. K consumed in registers (reg-direct scores);
// K/V register double-buffered across subtiles; barriers are LDS-only so the
// cache-write global stores never drain at a barrier.
__global__ __launch_bounds__(256) void attn_partial(
    const float* __restrict__ past_k, const float* __restrict__ past_v,
    const float* __restrict__ qkv, float* __restrict__ out_k,
    float* __restrict__ out_v, float* __restrict__ part) {
  const int t = threadIdx.x;
  const int c = blockIdx.x, h = blockIdx.y, b = blockIdx.z;
  const int bh = b * H_ + h;
  const int g = t & 31, rg = t >> 5;

  __shared__ float v_lds[SUBR * D_];   // 16KB linear [row][d]; reused for final reduce
  __shared__ float s_lds[SUBR * 9];    // raw scores, stride 9 (conflict-free)
  __shared__ float p_lds[SUBR * 12];   // [row][qi] padded to 12
  __shared__ float cm_lds[NQ], cs_lds[NQ];
  __shared__ float m_lds[2][NQ], l_lds[2][NQ];

  // Q resident in registers: this thread's fixed f4-column for all 8 q-rows
  float4 qreg[NQ];
#pragma unroll
  for (int qi = 0; qi < NQ; ++qi)
    qreg[qi] = *reinterpret_cast<const float4*>(
        &qkv[(size_t)(b * NQ + qi) * F3 + h * D_ + g * 4]);

  if (t < NQ) { m_lds[0][t] = -1e30f; l_lds[0][t] = 0.f; }

  const float* gk = past_k + ((size_t)bh * KVP + (size_t)c * CHUNK) * D_;
  const float* gv = past_v + ((size_t)bh * KVP + (size_t)c * CHUNK) * D_;
  float* ok = out_k + ((size_t)bh * KVT + (size_t)c * CHUNK) * D_;
  float* ov = out_v + ((size_t)bh * KVT + (size_t)c * CHUNK) * D_;

  const int w = t >> 6;               // wave id: PV row-slice owner
  const int lqg = (t >> 5) & 1;       // PV: q-group within wave
  const int dq = t & 31;              // PV: f4 d-column
  float acc[4][4];
#pragma unroll
  for (int i = 0; i < 4; ++i)
#pragma unroll
    for (int j = 0; j < 4; ++j) acc[i][j] = 0.f;

  const int b0 = g & 1, b1 = (g >> 1) & 1, b2 = (g >> 2) & 1;
  const int qsel = 4 * b0 + 2 * b1 + b2;  // qi this lane's reduced value maps to

  auto loadf = [&](float4 (&kf)[4], float4 (&vf)[4], int sub) {
    const size_t off = (size_t)sub * SUBR * D_;
#pragma unroll
    for (int i = 0; i < 4; ++i) {
      const size_t ga = off + (size_t)(rg + 8 * i) * D_ + g * 4;
      kf[i] = *reinterpret_cast<const float4*>(&gk[ga]);
      vf[i] = *reinterpret_cast<const float4*>(&gv[ga]);
    }
  };

  auto bodyf = [&](float4 (&kf)[4], float4 (&vf)[4], int sub) {
    const int cur = sub & 1, nxt = cur ^ 1;
    const size_t off = (size_t)sub * SUBR * D_;
    // ---- phase A: copy-through to cache, V->LDS, reg-direct scores ----
#pragma unroll
    for (int i = 0; i < 4; ++i) {
      const int r = rg + 8 * i;
      const size_t ga = off + (size_t)r * D_ + g * 4;
      *reinterpret_cast<float4*>(&ok[ga]) = kf[i];
      *reinterpret_cast<float4*>(&ov[ga]) = vf[i];
      *reinterpret_cast<float4*>(&v_lds[r * D_ + g * 4]) = vf[i];
      float sp[NQ];
#pragma unroll
      for (int qi = 0; qi < NQ; ++qi)
        sp[qi] = kf[i].x * qreg[qi].x + kf[i].y * qreg[qi].y +
                 kf[i].z * qreg[qi].z + kf[i].w * qreg[qi].w;
      // butterfly 8 vals -> 1 per lane over 32 lanes (row-group)
      float v1[4];
#pragma unroll
      for (int j = 0; j < 4; ++j) {
        float x = b0 ? sp[j] : sp[j + 4];
        v1[j] = (b0 ? sp[j + 4] : sp[j]) + __shfl_xor(x, 1);
      }
      float v2[2];
#pragma unroll
      for (int j = 0; j < 2; ++j) {
        float x = b1 ? v1[j] : v1[j + 2];
        v2[j] = (b1 ? v1[j + 2] : v1[j]) + __shfl_xor(x, 2);
      }
      float v3;
      {
        float x = b2 ? v2[0] : v2[1];
        v3 = (b2 ? v2[1] : v2[0]) + __shfl_xor(x, 4);
      }
      v3 += __shfl_xor(v3, 8);
      v3 += __shfl_xor(v3, 16);
      if (g < 8) s_lds[r * 9 + qsel] = v3;
    }
    LBAR();  // B1: s_lds + v_lds ready
    // ---- phase B: softmax over this subtile ----
    {
      const int srow = t & 31, sqi = t >> 5;
      float s = s_lds[srow * 9 + sqi] * SCALE;
      float cmax = s;
#pragma unroll
      for (int o = 16; o > 0; o >>= 1) cmax = fmaxf(cmax, __shfl_xor(cmax, o));
      float mo = m_lds[cur][sqi];
      float mn = fmaxf(mo, cmax);
      float p = __expf(s - mn);
      float psum = p;
#pragma unroll
      for (int o = 16; o > 0; o >>= 1) psum += __shfl_xor(psum, o);
      p_lds[srow * 12 + sqi] = p;
      if (srow == 0) { cm_lds[sqi] = cmax; cs_lds[sqi] = psum; }
    }
    LBAR();  // B2: p/cm/cs ready
    // ---- phase C: PV accumulate; wave w owns rows [8w, 8w+8) ----
    {
#pragma unroll
      for (int jq = 0; jq < 4; ++jq) {
        const int qi = lqg * 4 + jq;
        float mo = m_lds[cur][qi];
        float f = __expf(mo - fmaxf(mo, cm_lds[qi]));
        acc[jq][0] *= f; acc[jq][1] *= f; acc[jq][2] *= f; acc[jq][3] *= f;
      }
#pragma unroll
      for (int r8 = 0; r8 < 8; ++r8) {
        const int r = w * 8 + r8;
        float4 p4 = *reinterpret_cast<const float4*>(&p_lds[r * 12 + lqg * 4]);
        float4 v4 = *reinterpret_cast<const float4*>(&v_lds[r * D_ + dq * 4]);
        acc[0][0] += p4.x * v4.x; acc[0][1] += p4.x * v4.y; acc[0][2] += p4.x * v4.z; acc[0][3] += p4.x * v4.w;
        acc[1][0] += p4.y * v4.x; acc[1][1] += p4.y * v4.y; acc[1][2] += p4.y * v4.z; acc[1][3] += p4.y * v4.w;
        acc[2][0] += p4.z * v4.x; acc[2][1] += p4.z * v4.y; acc[2][2] += p4.z * v4.z; acc[2][3] += p4.z * v4.w;
        acc[3][0] += p4.w * v4.x; acc[3][1] += p4.w * v4.y; acc[3][2] += p4.w * v4.z; acc[3][3] += p4.w * v4.w;
      }
      if (t < NQ) {
        float mo = m_lds[cur][t];
        float mn = fmaxf(mo, cm_lds[t]);
        l_lds[nxt][t] = l_lds[cur][t] * __expf(mo - mn) + cs_lds[t];
        m_lds[nxt][t] = mn;
      }
    }
    LBAR();  // B3: PV done before LDS overwrite
  };

  float4 kfA[4], vfA[4], kfB[4], vfB[4];
  loadf(kfA, vfA, 0);
  LBAR();  // init (m/l) visible

  for (int sub = 0; sub < NSUB; sub += 2) {
    loadf(kfB, vfB, sub + 1);               // prefetch sub+1 (always valid, NSUB even)
    bodyf(kfA, vfA, sub);
    if (sub + 2 < NSUB) loadf(kfA, vfA, sub + 2);  // prefetch sub+2
    bodyf(kfB, vfB, sub + 1);
  }

  // ---- cross-wave partial-sum reduce through v_lds (exactly 4x1024 floats) ----
#pragma unroll
  for (int jq = 0; jq < 4; ++jq)
    *reinterpret_cast<float4*>(&v_lds[w * 1024 + (lqg * 4 + jq) * D_ + dq * 4]) =
        make_float4(acc[jq][0], acc[jq][1], acc[jq][2], acc[jq][3]);
  LBAR();

  float* pb = part + ((size_t)bh * NCHUNK + c) * PARTSZ;
  if (t < NQ) { pb[t] = m_lds[0][t]; pb[8 + t] = l_lds[0][t]; }  // NSUB even -> slot 0
  {
    float4 s0 = *reinterpret_cast<const float4*>(&v_lds[t * 4]);
    float4 s1 = *reinterpret_cast<const float4*>(&v_lds[1024 + t * 4]);
    float4 s2 = *reinterpret_cast<const float4*>(&v_lds[2048 + t * 4]);
    float4 s3 = *reinterpret_cast<const float4*>(&v_lds[3072 + t * 4]);
    float4 r4 = make_float4(s0.x + s1.x + s2.x + s3.x, s0.y + s1.y + s2.y + s3.y,
                            s0.z + s1.z + s2.z + s3.z, s0.w + s1.w + s2.w + s3.w);
    *reinterpret_cast<float4*>(&pb[16 + t * 4]) = r4;
  }
}

// ------- new-token chunk + combine partials -> attention output (pre-proj) -------
// grid: (H, B), 256 threads.
__global__ __launch_bounds__(256) void attn_combine(
    const float* __restrict__ qkv, const float* __restrict__ part,
    float* __restrict__ out_k, float* __restrict__ out_v,
    float* __restrict__ attn) {
  const int t = threadIdx.x;
  const int h = blockIdx.x, b = blockIdx.y;
  const int bh = b * H_ + h;
  __shared__ float q_lds[NQ * 132];
  __shared__ float kn_lds[NQ * 132];
  __shared__ float vn_lds[NQ * 132];
  __shared__ float p9[NQ * 12];
  __shared__ float m9_lds[NQ], s9_lds[NQ];
  {
    int n = t >> 5, g = t & 31;
    const float* src = &qkv[(size_t)(b * NQ + n) * F3 + h * D_ + g * 4];
    float4 qv = *reinterpret_cast<const float4*>(src);
    float4 kv = *reinterpret_cast<const float4*>(src + E_);
    float4 vv = *reinterpret_cast<const float4*>(src + 2 * E_);
    *reinterpret_cast<float4*>(&q_lds[n * 132 + g * 4]) = qv;
    *reinterpret_cast<float4*>(&kn_lds[n * 132 + g * 4]) = kv;
    *reinterpret_cast<float4*>(&vn_lds[n * 132 + g * 4]) = vv;
    *reinterpret_cast<float4*>(&out_k[((size_t)bh * KVT + KVP + n) * D_ + g * 4]) = kv;
    *reinterpret_cast<float4*>(&out_v[((size_t)bh * KVT + KVP + n) * D_ + g * 4]) = vv;
  }
  __syncthreads();
  if (t < 64) {
    int nq = t >> 3, nk = t & 7;
    float s = 0.f;
#pragma unroll
    for (int g = 0; g < 32; ++g) {
      float4 qv = *reinterpret_cast<const float4*>(&q_lds[nq * 132 + g * 4]);
      float4 kv = *reinterpret_cast<const float4*>(&kn_lds[nk * 132 + g * 4]);
      s += qv.x * kv.x + qv.y * kv.y + qv.z * kv.z + qv.w * kv.w;
    }
    s *= SCALE;
    float mx = s;
#pragma unroll
    for (int o = 4; o > 0; o >>= 1) mx = fmaxf(mx, __shfl_xor(mx, o));
    float p = __expf(s - mx);
    float sm = p;
#pragma unroll
    for (int o = 4; o > 0; o >>= 1) sm += __shfl_xor(sm, o);
    p9[nk * 12 + nq] = p;
    if (nk == 0) { m9_lds[nq] = mx; s9_lds[nq] = sm; }
  }
  __syncthreads();
  const int qg = t >> 7, dcol = t & 127;
  const float* pb = part + (size_t)bh * NCHUNK * PARTSZ;
#pragma unroll
  for (int jq = 0; jq < 4; ++jq) {
    int qi = qg * 4 + jq;
    float M = m9_lds[qi];
#pragma unroll
    for (int c = 0; c < NCHUNK; ++c) M = fmaxf(M, pb[(size_t)c * PARTSZ + qi]);
    float num = 0.f, den = 0.f;
#pragma unroll
    for (int c = 0; c < NCHUNK; ++c) {
      const float* pc = pb + (size_t)c * PARTSZ;
      float wgt = __expf(pc[qi] - M);
      den += wgt * pc[8 + qi];
      num += wgt * pc[16 + (size_t)qi * D_ + dcol];
    }
    float acc9 = 0.f;
#pragma unroll
    for (int r = 0; r < NQ; ++r) acc9 += p9[r * 12 + qi] * vn_lds[r * 132 + dcol];
    float w9 = __expf(m9_lds[qi] - M);
    num += w9 * acc9;
    den += w9 * s9_lds[qi];
    attn[((size_t)(b * NQ + qi)) * E_ + h * D_ + dcol] = num / den;
  }
}

extern "C" void kernel_launch(void* const* d_in, const int* in_sizes, int n_in,
                              void* d_out, int out_size, void* d_ws, size_t ws_size,
                              hipStream_t stream) {
  const float* x      = (const float*)d_in[0];
  const float* past_k = (const float*)d_in[1];
  const float* past_v = (const float*)d_in[2];
  const float* W_qkv  = (const float*)d_in[3];
  const float* W_out  = (const float*)d_in[4];

  float* out   = (float*)d_out;
  float* out_k = out + (size_t)B_ * NQ * E_;
  float* out_v = out_k + (size_t)B_ * H_ * KVT * D_;

  float* ws   = (float*)d_ws;
  float* qkv  = ws;                                       // 786432 floats
  float* part = qkv + (size_t)B_ * NQ * F3;               // 2129920 floats
  float* attn = part + (size_t)B_ * H_ * NCHUNK * PARTSZ; // 262144 floats

  // 1) fused QKV projection (384 blocks -> 1.5 waves/SIMD)
  gemm_xwt<64, 32><<<dim3(F3 / 32, 128 / 64), 256, 0, stream>>>(x, W_qkv, qkv, E_, F3);
  // 2) fused KV-cache copy + flash partials over past chunks
  attn_partial<<<dim3(NCHUNK, H_, B_), 256, 0, stream>>>(past_k, past_v, qkv, out_k, out_v, part);
  // 3) new-token chunk + combine -> attention output (pre out-proj)
  attn_combine<<<dim3(H_, B_), 256, 0, stream>>>(qkv, part, out_k, out_v, attn);
  // 4) output projection (256 blocks)
  gemm_xwt<32, 32><<<dim3(E_ / 32, 128 / 32), 256, 0, stream>>>(attn, W_out, out, E_, E_);
}

// Round 4
// 609.149 us; speedup vs baseline: 1.3218x; 1.3218x over previous
//
#include <hip/hip_runtime.h>
#include <cstddef>
#include <cstdint>

#define B_ 16
#define H_ 16
#define NQ 8
#define D_ 128
#define E_ 2048
#define F3 6144
#define KVP 4096
#define KVT 4104
#define SCALE 0.08838834764831843f
#define NCHUNK 8
#define CHUNK 512
#define SUBR 32
#define NSUB 16
#define PARTSZ 1040  // 8 m + 8 l + 8*128 acc

// ---------------- GEMM: C[M][F] = X[M][K] * W[F][K]^T (fp32) ----------------
template <int BM, int BN>
__global__ __launch_bounds__(256) void gemm_xwt(const float* __restrict__ X,
                                                const float* __restrict__ W,
                                                float* __restrict__ C,
                                                int K, int Fdim) {
  constexpr int BK = 32;
  constexpr int RM = BM / 16;
  constexpr int RN = BN / 16;
  __shared__ float xs[BK][BM + 4];
  __shared__ float wss[BK][BN + 4];
  const int t = threadIdx.x;
  const int tm = t >> 4, tn = t & 15;
  const int m0 = blockIdx.y * BM, f0 = blockIdx.x * BN;
  float acc[RM][RN];
#pragma unroll
  for (int i = 0; i < RM; ++i)
#pragma unroll
    for (int j = 0; j < RN; ++j) acc[i][j] = 0.f;

  for (int kk = 0; kk < K; kk += BK) {
#pragma unroll
    for (int i = 0; i < (BM * BK) / 1024; ++i) {
      int j = t + i * 256;
      int r = j >> 3;
      int c = (j & 7) << 2;
      float4 v = *reinterpret_cast<const float4*>(&X[(size_t)(m0 + r) * K + kk + c]);
      xs[c + 0][r] = v.x; xs[c + 1][r] = v.y; xs[c + 2][r] = v.z; xs[c + 3][r] = v.w;
    }
#pragma unroll
    for (int i = 0; i < (BN * BK) / 1024; ++i) {
      int j = t + i * 256;
      int r = j >> 3;
      int c = (j & 7) << 2;
      float4 v = *reinterpret_cast<const float4*>(&W[(size_t)(f0 + r) * K + kk + c]);
      wss[c + 0][r] = v.x; wss[c + 1][r] = v.y; wss[c + 2][r] = v.z; wss[c + 3][r] = v.w;
    }
    __syncthreads();
#pragma unroll
    for (int k = 0; k < BK; ++k) {
      float xv[RM], wv[RN];
      if constexpr (RM == 4) {
        *reinterpret_cast<float4*>(xv) = *reinterpret_cast<const float4*>(&xs[k][tm * 4]);
      } else {
        *reinterpret_cast<float2*>(xv) = *reinterpret_cast<const float2*>(&xs[k][tm * 2]);
      }
      if constexpr (RN == 4) {
        *reinterpret_cast<float4*>(wv) = *reinterpret_cast<const float4*>(&wss[k][tn * 4]);
      } else {
        *reinterpret_cast<float2*>(wv) = *reinterpret_cast<const float2*>(&wss[k][tn * 2]);
      }
#pragma unroll
      for (int i = 0; i < RM; ++i)
#pragma unroll
        for (int j = 0; j < RN; ++j) acc[i][j] += xv[i] * wv[j];
    }
    __syncthreads();
  }
#pragma unroll
  for (int i = 0; i < RM; ++i) {
    float* cp = &C[(size_t)(m0 + tm * RM + i) * Fdim + f0 + tn * RN];
    if constexpr (RN == 4) {
      *reinterpret_cast<float4*>(cp) = make_float4(acc[i][0], acc[i][1], acc[i][2], acc[i][3]);
    } else {
      *reinterpret_cast<float2*>(cp) = make_float2(acc[i][0], acc[i][1]);
    }
  }
}

// ------- Fused KV-cache copy + flash-attention partials over past chunks -------
// grid: (NCHUNK, H, B), 256 threads. K AND V both consumed in registers; only
// scores (1KB) and P (1KB) go through LDS. 2 barriers per 32-row subtile.
// Thread (g=t&31, rg=t>>5) owns rows rg+8i (i<4), f4-columns 4g..4g+3.
__global__ __launch_bounds__(256) void attn_partial(
    const float* __restrict__ past_k, const float* __restrict__ past_v,
    const float* __restrict__ qkv, float* __restrict__ out_k,
    float* __restrict__ out_v, float* __restrict__ part) {
  const int t = threadIdx.x;
  const int c = blockIdx.x, h = blockIdx.y, b = blockIdx.z;
  const int bh = b * H_ + h;
  const int g = t & 31, rg = t >> 5;

  __shared__ float red[4096];           // 16KB: [0..288)=s_lds, [288..544)=p_lds; end-reduce buffer
  __shared__ float f_lds[NQ];           // per-subtile rescale factors
  __shared__ float m_lds[2][NQ], l_lds[2][NQ];
  float* s_lds = red;                   // stride 9: s_lds[r*9+qi]
  float* p_lds = red + 288;             // stride 8 (b128-readable): p_lds[r*8+qi]

  // Q resident in registers: this thread's fixed f4-column for all 8 q-rows
  float4 qreg[NQ];
#pragma unroll
  for (int qi = 0; qi < NQ; ++qi)
    qreg[qi] = *reinterpret_cast<const float4*>(
        &qkv[(size_t)(b * NQ + qi) * F3 + h * D_ + g * 4]);

  if (t < NQ) { m_lds[0][t] = -1e30f; l_lds[0][t] = 0.f; }

  const float* gk = past_k + ((size_t)bh * KVP + (size_t)c * CHUNK) * D_;
  const float* gv = past_v + ((size_t)bh * KVP + (size_t)c * CHUNK) * D_;
  float* ok = out_k + ((size_t)bh * KVT + (size_t)c * CHUNK) * D_;
  float* ov = out_v + ((size_t)bh * KVT + (size_t)c * CHUNK) * D_;

  float4 acc[NQ];  // acc[qi] = partial out[qi][4g..4g+3] over this thread's rows
#pragma unroll
  for (int qi = 0; qi < NQ; ++qi) acc[qi] = make_float4(0.f, 0.f, 0.f, 0.f);

  const int b0 = g & 1, b1 = (g >> 1) & 1, b2 = (g >> 2) & 1;
  const int qsel = 4 * b0 + 2 * b1 + b2;  // qi this lane's reduced value maps to

  __syncthreads();  // m/l init visible

  for (int sub = 0; sub < NSUB; ++sub) {
    const int cur = sub & 1, nxt = cur ^ 1;
    const size_t off = (size_t)sub * SUBR * D_;

    // ---- phase A: load K/V rows, copy-through to cache, reg-direct scores ----
    float4 kf[4], vf[4];
#pragma unroll
    for (int i = 0; i < 4; ++i) {
      const size_t ga = off + (size_t)(rg + 8 * i) * D_ + g * 4;
      kf[i] = *reinterpret_cast<const float4*>(&gk[ga]);
      vf[i] = *reinterpret_cast<const float4*>(&gv[ga]);
    }
#pragma unroll
    for (int i = 0; i < 4; ++i) {
      const int r = rg + 8 * i;
      const size_t ga = off + (size_t)r * D_ + g * 4;
      *reinterpret_cast<float4*>(&ok[ga]) = kf[i];
      *reinterpret_cast<float4*>(&ov[ga]) = vf[i];
      float sp[NQ];
#pragma unroll
      for (int qi = 0; qi < NQ; ++qi)
        sp[qi] = kf[i].x * qreg[qi].x + kf[i].y * qreg[qi].y +
                 kf[i].z * qreg[qi].z + kf[i].w * qreg[qi].w;
      // butterfly: 8 vals -> 1 per lane over the 32-lane half-wave
      float v1[4];
#pragma unroll
      for (int j = 0; j < 4; ++j) {
        float x = b0 ? sp[j] : sp[j + 4];
        v1[j] = (b0 ? sp[j + 4] : sp[j]) + __shfl_xor(x, 1);
      }
      float v2[2];
#pragma unroll
      for (int j = 0; j < 2; ++j) {
        float x = b1 ? v1[j] : v1[j + 2];
        v2[j] = (b1 ? v1[j + 2] : v1[j]) + __shfl_xor(x, 2);
      }
      float v3;
      {
        float x = b2 ? v2[0] : v2[1];
        v3 = (b2 ? v2[1] : v2[0]) + __shfl_xor(x, 4);
      }
      v3 += __shfl_xor(v3, 8);
      v3 += __shfl_xor(v3, 16);
      if (g < 8) s_lds[r * 9 + qsel] = v3;
    }
    __syncthreads();  // B1: s_lds ready

    // ---- phase B: softmax; srow==0 lane publishes f, m, l per qi ----
    {
      const int srow = t & 31, sqi = t >> 5;
      float s = s_lds[srow * 9 + sqi] * SCALE;
      float cmax = s;
#pragma unroll
      for (int o = 16; o > 0; o >>= 1) cmax = fmaxf(cmax, __shfl_xor(cmax, o));
      float mo = m_lds[cur][sqi];
      float mn = fmaxf(mo, cmax);
      float p = __expf(s - mn);
      float psum = p;
#pragma unroll
      for (int o = 16; o > 0; o >>= 1) psum += __shfl_xor(psum, o);
      p_lds[srow * 8 + sqi] = p;
      if (srow == 0) {
        float f = __expf(mo - mn);
        f_lds[sqi] = f;
        m_lds[nxt][sqi] = mn;
        l_lds[nxt][sqi] = l_lds[cur][sqi] * f + psum;
      }
    }
    __syncthreads();  // B2: p/f ready

    // ---- phase C: per-thread PV on register V rows ----
    {
      float4 f0 = *reinterpret_cast<const float4*>(&f_lds[0]);
      float4 f1 = *reinterpret_cast<const float4*>(&f_lds[4]);
      acc[0].x *= f0.x; acc[0].y *= f0.x; acc[0].z *= f0.x; acc[0].w *= f0.x;
      acc[1].x *= f0.y; acc[1].y *= f0.y; acc[1].z *= f0.y; acc[1].w *= f0.y;
      acc[2].x *= f0.z; acc[2].y *= f0.z; acc[2].z *= f0.z; acc[2].w *= f0.z;
      acc[3].x *= f0.w; acc[3].y *= f0.w; acc[3].z *= f0.w; acc[3].w *= f0.w;
      acc[4].x *= f1.x; acc[4].y *= f1.x; acc[4].z *= f1.x; acc[4].w *= f1.x;
      acc[5].x *= f1.y; acc[5].y *= f1.y; acc[5].z *= f1.y; acc[5].w *= f1.y;
      acc[6].x *= f1.z; acc[6].y *= f1.z; acc[6].z *= f1.z; acc[6].w *= f1.z;
      acc[7].x *= f1.w; acc[7].y *= f1.w; acc[7].z *= f1.w; acc[7].w *= f1.w;
#pragma unroll
      for (int i = 0; i < 4; ++i) {
        const int r = rg + 8 * i;
        float4 pa = *reinterpret_cast<const float4*>(&p_lds[r * 8]);      // broadcast
        float4 pc = *reinterpret_cast<const float4*>(&p_lds[r * 8 + 4]);  // broadcast
        acc[0].x += pa.x * vf[i].x; acc[0].y += pa.x * vf[i].y; acc[0].z += pa.x * vf[i].z; acc[0].w += pa.x * vf[i].w;
        acc[1].x += pa.y * vf[i].x; acc[1].y += pa.y * vf[i].y; acc[1].z += pa.y * vf[i].z; acc[1].w += pa.y * vf[i].w;
        acc[2].x += pa.z * vf[i].x; acc[2].y += pa.z * vf[i].y; acc[2].z += pa.z * vf[i].z; acc[2].w += pa.z * vf[i].w;
        acc[3].x += pa.w * vf[i].x; acc[3].y += pa.w * vf[i].y; acc[3].z += pa.w * vf[i].z; acc[3].w += pa.w * vf[i].w;
        acc[4].x += pc.x * vf[i].x; acc[4].y += pc.x * vf[i].y; acc[4].z += pc.x * vf[i].z; acc[4].w += pc.x * vf[i].w;
        acc[5].x += pc.y * vf[i].x; acc[5].y += pc.y * vf[i].y; acc[5].z += pc.y * vf[i].z; acc[5].w += pc.y * vf[i].w;
        acc[6].x += pc.z * vf[i].x; acc[6].y += pc.z * vf[i].y; acc[6].z += pc.z * vf[i].z; acc[6].w += pc.z * vf[i].w;
        acc[7].x += pc.w * vf[i].x; acc[7].y += pc.w * vf[i].y; acc[7].z += pc.w * vf[i].z; acc[7].w += pc.w * vf[i].w;
      }
    }
    // no barrier here: phase A(sub+1) writes s_lds only after all threads passed B2;
    // p_lds rewritten only in B(sub+1), which is after B1(sub+1).
  }

  __syncthreads();  // all phase-C p_lds reads done before red[] is clobbered

  // ---- cross-rg reduction tree: 8 -> 4 -> 2 -> 1 row-groups ----
#pragma unroll
  for (int half = 4; half >= 1; half >>= 1) {
    if (rg >= half && rg < 2 * half) {
#pragma unroll
      for (int qi = 0; qi < NQ; ++qi)
        *reinterpret_cast<float4*>(&red[(rg - half) * 1024 + qi * 128 + g * 4]) = acc[qi];
    }
    __syncthreads();
    if (rg < half) {
#pragma unroll
      for (int qi = 0; qi < NQ; ++qi) {
        float4 o = *reinterpret_cast<const float4*>(&red[rg * 1024 + qi * 128 + g * 4]);
        acc[qi].x += o.x; acc[qi].y += o.y; acc[qi].z += o.z; acc[qi].w += o.w;
      }
    }
    __syncthreads();
  }

  // ---- emit partials: [m(8) | l(8) | acc(8x128)] ----
  float* pb = part + ((size_t)bh * NCHUNK + c) * PARTSZ;
  if (t < NQ) { pb[t] = m_lds[0][t]; pb[8 + t] = l_lds[0][t]; }  // NSUB even -> slot 0
  if (rg == 0) {
#pragma unroll
    for (int qi = 0; qi < NQ; ++qi)
      *reinterpret_cast<float4*>(&pb[16 + qi * 128 + g * 4]) = acc[qi];
  }
}

// ------- new-token chunk + combine partials -> attention output (pre-proj) -------
// grid: (H, B), 256 threads.
__global__ __launch_bounds__(256) void attn_combine(
    const float* __restrict__ qkv, const float* __restrict__ part,
    float* __restrict__ out_k, float* __restrict__ out_v,
    float* __restrict__ attn) {
  const int t = threadIdx.x;
  const int h = blockIdx.x, b = blockIdx.y;
  const int bh = b * H_ + h;
  __shared__ float q_lds[NQ * 132];
  __shared__ float kn_lds[NQ * 132];
  __shared__ float vn_lds[NQ * 132];
  __shared__ float p9[NQ * 12];
  __shared__ float m9_lds[NQ], s9_lds[NQ];
  {
    int n = t >> 5, g = t & 31;
    const float* src = &qkv[(size_t)(b * NQ + n) * F3 + h * D_ + g * 4];
    float4 qv = *reinterpret_cast<const float4*>(src);
    float4 kv = *reinterpret_cast<const float4*>(src + E_);
    float4 vv = *reinterpret_cast<const float4*>(src + 2 * E_);
    *reinterpret_cast<float4*>(&q_lds[n * 132 + g * 4]) = qv;
    *reinterpret_cast<float4*>(&kn_lds[n * 132 + g * 4]) = kv;
    *reinterpret_cast<float4*>(&vn_lds[n * 132 + g * 4]) = vv;
    *reinterpret_cast<float4*>(&out_k[((size_t)bh * KVT + KVP + n) * D_ + g * 4]) = kv;
    *reinterpret_cast<float4*>(&out_v[((size_t)bh * KVT + KVP + n) * D_ + g * 4]) = vv;
  }
  __syncthreads();
  if (t < 64) {
    int nq = t >> 3, nk = t & 7;
    float s = 0.f;
#pragma unroll
    for (int g = 0; g < 32; ++g) {
      float4 qv = *reinterpret_cast<const float4*>(&q_lds[nq * 132 + g * 4]);
      float4 kv = *reinterpret_cast<const float4*>(&kn_lds[nk * 132 + g * 4]);
      s += qv.x * kv.x + qv.y * kv.y + qv.z * kv.z + qv.w * kv.w;
    }
    s *= SCALE;
    float mx = s;
#pragma unroll
    for (int o = 4; o > 0; o >>= 1) mx = fmaxf(mx, __shfl_xor(mx, o));
    float p = __expf(s - mx);
    float sm = p;
#pragma unroll
    for (int o = 4; o > 0; o >>= 1) sm += __shfl_xor(sm, o);
    p9[nk * 12 + nq] = p;
    if (nk == 0) { m9_lds[nq] = mx; s9_lds[nq] = sm; }
  }
  __syncthreads();
  const int qg = t >> 7, dcol = t & 127;
  const float* pb = part + (size_t)bh * NCHUNK * PARTSZ;
#pragma unroll
  for (int jq = 0; jq < 4; ++jq) {
    int qi = qg * 4 + jq;
    float M = m9_lds[qi];
#pragma unroll
    for (int c = 0; c < NCHUNK; ++c) M = fmaxf(M, pb[(size_t)c * PARTSZ + qi]);
    float num = 0.f, den = 0.f;
#pragma unroll
    for (int c = 0; c < NCHUNK; ++c) {
      const float* pc = pb + (size_t)c * PARTSZ;
      float wgt = __expf(pc[qi] - M);
      den += wgt * pc[8 + qi];
      num += wgt * pc[16 + (size_t)qi * D_ + dcol];
    }
    float acc9 = 0.f;
#pragma unroll
    for (int r = 0; r < NQ; ++r) acc9 += p9[r * 12 + qi] * vn_lds[r * 132 + dcol];
    float w9 = __expf(m9_lds[qi] - M);
    num += w9 * acc9;
    den += w9 * s9_lds[qi];
    attn[((size_t)(b * NQ + qi)) * E_ + h * D_ + dcol] = num / den;
  }
}

extern "C" void kernel_launch(void* const* d_in, const int* in_sizes, int n_in,
                              void* d_out, int out_size, void* d_ws, size_t ws_size,
                              hipStream_t stream) {
  const float* x      = (const float*)d_in[0];
  const float* past_k = (const float*)d_in[1];
  const float* past_v = (const float*)d_in[2];
  const float* W_qkv  = (const float*)d_in[3];
  const float* W_out  = (const float*)d_in[4];

  float* out   = (float*)d_out;
  float* out_k = out + (size_t)B_ * NQ * E_;
  float* out_v = out_k + (size_t)B_ * H_ * KVT * D_;

  float* ws   = (float*)d_ws;
  float* qkv  = ws;                                       // 786432 floats
  float* part = qkv + (size_t)B_ * NQ * F3;               // 2129920 floats
  float* attn = part + (size_t)B_ * H_ * NCHUNK * PARTSZ; // 262144 floats

  // 1) fused QKV projection
  gemm_xwt<64, 32><<<dim3(F3 / 32, 128 / 64), 256, 0, stream>>>(x, W_qkv, qkv, E_, F3);
  // 2) fused KV-cache copy + flash partials over past chunks
  attn_partial<<<dim3(NCHUNK, H_, B_), 256, 0, stream>>>(past_k, past_v, qkv, out_k, out_v, part);
  // 3) new-token chunk + combine -> attention output (pre out-proj)
  attn_combine<<<dim3(H_, B_), 256, 0, stream>>>(qkv, part, out_k, out_v, attn);
  // 4) output projection
  gemm_xwt<32, 32><<<dim3(E_ / 32, 128 / 32), 256, 0, stream>>>(attn, W_out, out, E_, E_);
}

// Round 6
// 567.955 us; speedup vs baseline: 1.4176x; 1.0725x over previous
//
#include <hip/hip_runtime.h>
#include <cstddef>
#include <cstdint>

#define B_ 16
#define H_ 16
#define NQ 8
#define D_ 128
#define E_ 2048
#define F3 6144
#define KVP 4096
#define KVT 4104
#define SCALE 0.08838834764831843f
#define NCHUNK 8
#define CHUNK 512
#define SUBR 32
#define NSUB 16
#define PARTSZ 1040  // 8 m + 8 l + 8*128 acc

typedef float f32x4_t __attribute__((ext_vector_type(4)));

__device__ __forceinline__ void nt_store4(float* p, float4 v) {
  f32x4_t w;
  w.x = v.x; w.y = v.y; w.z = v.z; w.w = v.w;
  __builtin_nontemporal_store(w, reinterpret_cast<f32x4_t*>(p));
}

// ---------------- GEMM: C[M][F] = X[M][K] * W[F][K]^T (fp32) ----------------
// SPLITK>1: block z writes its partial to C + z*128*Fdim (separate buffers, no atomics).
template <int BM, int BN, int SPLITK>
__global__ __launch_bounds__(256) void gemm_xwt(const float* __restrict__ X,
                                                const float* __restrict__ W,
                                                float* __restrict__ C,
                                                int K, int Fdim) {
  constexpr int BK = 32;
  constexpr int RM = BM / 16;
  constexpr int RN = BN / 16;
  __shared__ float xs[BK][BM + 4];
  __shared__ float wss[BK][BN + 4];
  const int t = threadIdx.x;
  const int tm = t >> 4, tn = t & 15;
  const int m0 = blockIdx.y * BM, f0 = blockIdx.x * BN;
  const int kbeg = (SPLITK > 1) ? blockIdx.z * (K / SPLITK) : 0;
  const int kend = (SPLITK > 1) ? kbeg + K / SPLITK : K;
  if (SPLITK > 1) C += (size_t)blockIdx.z * 128 * Fdim;
  float acc[RM][RN];
#pragma unroll
  for (int i = 0; i < RM; ++i)
#pragma unroll
    for (int j = 0; j < RN; ++j) acc[i][j] = 0.f;

  for (int kk = kbeg; kk < kend; kk += BK) {
#pragma unroll
    for (int i = 0; i < (BM * BK) / 1024; ++i) {
      int j = t + i * 256;
      int r = j >> 3;
      int c = (j & 7) << 2;
      float4 v = *reinterpret_cast<const float4*>(&X[(size_t)(m0 + r) * K + kk + c]);
      xs[c + 0][r] = v.x; xs[c + 1][r] = v.y; xs[c + 2][r] = v.z; xs[c + 3][r] = v.w;
    }
#pragma unroll
    for (int i = 0; i < (BN * BK) / 1024; ++i) {
      int j = t + i * 256;
      int r = j >> 3;
      int c = (j & 7) << 2;
      float4 v = *reinterpret_cast<const float4*>(&W[(size_t)(f0 + r) * K + kk + c]);
      wss[c + 0][r] = v.x; wss[c + 1][r] = v.y; wss[c + 2][r] = v.z; wss[c + 3][r] = v.w;
    }
    __syncthreads();
#pragma unroll
    for (int k = 0; k < BK; ++k) {
      float xv[RM], wv[RN];
      if constexpr (RM == 4) {
        *reinterpret_cast<float4*>(xv) = *reinterpret_cast<const float4*>(&xs[k][tm * 4]);
      } else {
        *reinterpret_cast<float2*>(xv) = *reinterpret_cast<const float2*>(&xs[k][tm * 2]);
      }
      if constexpr (RN == 4) {
        *reinterpret_cast<float4*>(wv) = *reinterpret_cast<const float4*>(&wss[k][tn * 4]);
      } else {
        *reinterpret_cast<float2*>(wv) = *reinterpret_cast<const float2*>(&wss[k][tn * 2]);
      }
#pragma unroll
      for (int i = 0; i < RM; ++i)
#pragma unroll
        for (int j = 0; j < RN; ++j) acc[i][j] += xv[i] * wv[j];
    }
    __syncthreads();
  }
#pragma unroll
  for (int i = 0; i < RM; ++i) {
    float* cp = &C[(size_t)(m0 + tm * RM + i) * Fdim + f0 + tn * RN];
    if constexpr (RN == 4) {
      *reinterpret_cast<float4*>(cp) = make_float4(acc[i][0], acc[i][1], acc[i][2], acc[i][3]);
    } else {
      *reinterpret_cast<float2*>(cp) = make_float2(acc[i][0], acc[i][1]);
    }
  }
}

// o = a + b, n4 float4s, grid*block == n4
__global__ __launch_bounds__(256) void add2(const float* __restrict__ a,
                                            const float* __restrict__ b,
                                            float* __restrict__ o) {
  int i = blockIdx.x * 256 + threadIdx.x;
  float4 va = reinterpret_cast<const float4*>(a)[i];
  float4 vb = reinterpret_cast<const float4*>(b)[i];
  reinterpret_cast<float4*>(o)[i] =
      make_float4(va.x + vb.x, va.y + vb.y, va.z + vb.z, va.w + vb.w);
}

// ------- Fused KV-cache copy + flash-attention partials over past chunks -------
// grid: (NCHUNK, H, B), 256 threads. K AND V consumed in registers; K/V of sub+1
// prefetched after the B2 barrier (hidden under PV FMAs). NT copy-through stores.
__global__ __launch_bounds__(256) void attn_partial(
    const float* __restrict__ past_k, const float* __restrict__ past_v,
    const float* __restrict__ qkv_a, const float* __restrict__ qkv_b,
    float* __restrict__ out_k, float* __restrict__ out_v,
    float* __restrict__ part) {
  const int t = threadIdx.x;
  const int c = blockIdx.x, h = blockIdx.y, b = blockIdx.z;
  const int bh = b * H_ + h;
  const int g = t & 31, rg = t >> 5;

  __shared__ float red[4096];           // 16KB: s_lds/p_lds overlay; end-reduce buffer
  __shared__ float f_lds[NQ];
  __shared__ float m_lds[2][NQ], l_lds[2][NQ];
  float* s_lds = red;                   // stride 9: s_lds[r*9+qi]
  float* p_lds = red + 288;             // stride 8: p_lds[r*8+qi]

  // Q resident in registers (sum of split-K partials)
  float4 qreg[NQ];
#pragma unroll
  for (int qi = 0; qi < NQ; ++qi) {
    const size_t qoff = (size_t)(b * NQ + qi) * F3 + h * D_ + g * 4;
    float4 q0 = *reinterpret_cast<const float4*>(&qkv_a[qoff]);
    if (qkv_b) {
      float4 q1 = *reinterpret_cast<const float4*>(&qkv_b[qoff]);
      q0.x += q1.x; q0.y += q1.y; q0.z += q1.z; q0.w += q1.w;
    }
    qreg[qi] = q0;
  }

  if (t < NQ) { m_lds[0][t] = -1e30f; l_lds[0][t] = 0.f; }

  const float* gk = past_k + ((size_t)bh * KVP + (size_t)c * CHUNK) * D_;
  const float* gv = past_v + ((size_t)bh * KVP + (size_t)c * CHUNK) * D_;
  float* ok = out_k + ((size_t)bh * KVT + (size_t)c * CHUNK) * D_;
  float* ov = out_v + ((size_t)bh * KVT + (size_t)c * CHUNK) * D_;

  float4 acc[NQ];
#pragma unroll
  for (int qi = 0; qi < NQ; ++qi) acc[qi] = make_float4(0.f, 0.f, 0.f, 0.f);

  const int b0 = g & 1, b1 = (g >> 1) & 1, b2 = (g >> 2) & 1;
  const int qsel = 4 * b0 + 2 * b1 + b2;

  auto loadf = [&](float4 (&kf)[4], float4 (&vf)[4], int sub) {
    const size_t off = (size_t)sub * SUBR * D_;
#pragma unroll
    for (int i = 0; i < 4; ++i) {
      const size_t ga = off + (size_t)(rg + 8 * i) * D_ + g * 4;
      kf[i] = *reinterpret_cast<const float4*>(&gk[ga]);
      vf[i] = *reinterpret_cast<const float4*>(&gv[ga]);
    }
  };

  auto bodyf = [&](float4 (&kf)[4], float4 (&vf)[4], float4 (&kfN)[4],
                   float4 (&vfN)[4], int sub, bool pf) {
    const int cur = sub & 1, nxt = cur ^ 1;
    const size_t off = (size_t)sub * SUBR * D_;
    // ---- phase A: copy-through (NT) + reg-direct scores ----
#pragma unroll
    for (int i = 0; i < 4; ++i) {
      const int r = rg + 8 * i;
      const size_t ga = off + (size_t)r * D_ + g * 4;
      nt_store4(&ok[ga], kf[i]);
      nt_store4(&ov[ga], vf[i]);
      float sp[NQ];
#pragma unroll
      for (int qi = 0; qi < NQ; ++qi)
        sp[qi] = kf[i].x * qreg[qi].x + kf[i].y * qreg[qi].y +
                 kf[i].z * qreg[qi].z + kf[i].w * qreg[qi].w;
      // butterfly: 8 vals -> 1 per lane over the 32-lane half-wave
      float v1[4];
#pragma unroll
      for (int j = 0; j < 4; ++j) {
        float x = b0 ? sp[j] : sp[j + 4];
        v1[j] = (b0 ? sp[j + 4] : sp[j]) + __shfl_xor(x, 1);
      }
      float v2[2];
#pragma unroll
      for (int j = 0; j < 2; ++j) {
        float x = b1 ? v1[j] : v1[j + 2];
        v2[j] = (b1 ? v1[j + 2] : v1[j]) + __shfl_xor(x, 2);
      }
      float v3;
      {
        float x = b2 ? v2[0] : v2[1];
        v3 = (b2 ? v2[1] : v2[0]) + __shfl_xor(x, 4);
      }
      v3 += __shfl_xor(v3, 8);
      v3 += __shfl_xor(v3, 16);
      if (g < 8) s_lds[r * 9 + qsel] = v3;
    }
    __syncthreads();  // B1: s_lds ready

    // ---- phase B: softmax; srow==0 lane publishes f, m, l per qi ----
    {
      const int srow = t & 31, sqi = t >> 5;
      float s = s_lds[srow * 9 + sqi] * SCALE;
      float cmax = s;
#pragma unroll
      for (int o = 16; o > 0; o >>= 1) cmax = fmaxf(cmax, __shfl_xor(cmax, o));
      float mo = m_lds[cur][sqi];
      float mn = fmaxf(mo, cmax);
      float p = __expf(s - mn);
      float psum = p;
#pragma unroll
      for (int o = 16; o > 0; o >>= 1) psum += __shfl_xor(psum, o);
      p_lds[srow * 8 + sqi] = p;
      if (srow == 0) {
        float f = __expf(mo - mn);
        f_lds[sqi] = f;
        m_lds[nxt][sqi] = mn;
        l_lds[nxt][sqi] = l_lds[cur][sqi] * f + psum;
      }
    }
    __syncthreads();  // B2: p/f ready

    // ---- prefetch next subtile's K/V (hidden under phase C FMAs) ----
    if (pf) loadf(kfN, vfN, sub + 1);

    // ---- phase C: per-thread PV on register V rows ----
    {
      float4 f0 = *reinterpret_cast<const float4*>(&f_lds[0]);
      float4 f1 = *reinterpret_cast<const float4*>(&f_lds[4]);
      acc[0].x *= f0.x; acc[0].y *= f0.x; acc[0].z *= f0.x; acc[0].w *= f0.x;
      acc[1].x *= f0.y; acc[1].y *= f0.y; acc[1].z *= f0.y; acc[1].w *= f0.y;
      acc[2].x *= f0.z; acc[2].y *= f0.z; acc[2].z *= f0.z; acc[2].w *= f0.z;
      acc[3].x *= f0.w; acc[3].y *= f0.w; acc[3].z *= f0.w; acc[3].w *= f0.w;
      acc[4].x *= f1.x; acc[4].y *= f1.x; acc[4].z *= f1.x; acc[4].w *= f1.x;
      acc[5].x *= f1.y; acc[5].y *= f1.y; acc[5].z *= f1.y; acc[5].w *= f1.y;
      acc[6].x *= f1.z; acc[6].y *= f1.z; acc[6].z *= f1.z; acc[6].w *= f1.z;
      acc[7].x *= f1.w; acc[7].y *= f1.w; acc[7].z *= f1.w; acc[7].w *= f1.w;
#pragma unroll
      for (int i = 0; i < 4; ++i) {
        const int r = rg + 8 * i;
        float4 pa = *reinterpret_cast<const float4*>(&p_lds[r * 8]);      // broadcast
        float4 pc = *reinterpret_cast<const float4*>(&p_lds[r * 8 + 4]);  // broadcast
        acc[0].x += pa.x * vf[i].x; acc[0].y += pa.x * vf[i].y; acc[0].z += pa.x * vf[i].z; acc[0].w += pa.x * vf[i].w;
        acc[1].x += pa.y * vf[i].x; acc[1].y += pa.y * vf[i].y; acc[1].z += pa.y * vf[i].z; acc[1].w += pa.y * vf[i].w;
        acc[2].x += pa.z * vf[i].x; acc[2].y += pa.z * vf[i].y; acc[2].z += pa.z * vf[i].z; acc[2].w += pa.z * vf[i].w;
        acc[3].x += pa.w * vf[i].x; acc[3].y += pa.w * vf[i].y; acc[3].z += pa.w * vf[i].z; acc[3].w += pa.w * vf[i].w;
        acc[4].x += pc.x * vf[i].x; acc[4].y += pc.x * vf[i].y; acc[4].z += pc.x * vf[i].z; acc[4].w += pc.x * vf[i].w;
        acc[5].x += pc.y * vf[i].x; acc[5].y += pc.y * vf[i].y; acc[5].z += pc.y * vf[i].z; acc[5].w += pc.y * vf[i].w;
        acc[6].x += pc.z * vf[i].x; acc[6].y += pc.z * vf[i].y; acc[6].z += pc.z * vf[i].z; acc[6].w += pc.z * vf[i].w;
        acc[7].x += pc.w * vf[i].x; acc[7].y += pc.w * vf[i].y; acc[7].z += pc.w * vf[i].z; acc[7].w += pc.w * vf[i].w;
      }
    }
    // no barrier: A(sub+1) writes s_lds only after all threads passed B2;
    // p_lds rewritten only after B1(sub+1).
  };

  __syncthreads();  // m/l init visible

  float4 kfA[4], vfA[4], kfB[4], vfB[4];
  loadf(kfA, vfA, 0);
  for (int sub = 0; sub < NSUB; sub += 2) {
    bodyf(kfA, vfA, kfB, vfB, sub, true);
    bodyf(kfB, vfB, kfA, vfA, sub + 1, sub + 2 < NSUB);
  }

  __syncthreads();  // all phase-C p_lds reads done before red[] is clobbered

  // ---- cross-rg reduction tree: 8 -> 4 -> 2 -> 1 row-groups ----
#pragma unroll
  for (int half = 4; half >= 1; half >>= 1) {
    if (rg >= half && rg < 2 * half) {
#pragma unroll
      for (int qi = 0; qi < NQ; ++qi)
        *reinterpret_cast<float4*>(&red[(rg - half) * 1024 + qi * 128 + g * 4]) = acc[qi];
    }
    __syncthreads();
    if (rg < half) {
#pragma unroll
      for (int qi = 0; qi < NQ; ++qi) {
        float4 o = *reinterpret_cast<const float4*>(&red[rg * 1024 + qi * 128 + g * 4]);
        acc[qi].x += o.x; acc[qi].y += o.y; acc[qi].z += o.z; acc[qi].w += o.w;
      }
    }
    __syncthreads();
  }

  // ---- emit partials: [m(8) | l(8) | acc(8x128)] ----
  float* pb = part + ((size_t)bh * NCHUNK + c) * PARTSZ;
  if (t < NQ) { pb[t] = m_lds[0][t]; pb[8 + t] = l_lds[0][t]; }  // NSUB even -> slot 0
  if (rg == 0) {
#pragma unroll
    for (int qi = 0; qi < NQ; ++qi)
      *reinterpret_cast<float4*>(&pb[16 + qi * 128 + g * 4]) = acc[qi];
  }
}

// ------- new-token chunk + combine partials -> attention output (pre-proj) -------
// grid: (H, B), 256 threads.
__global__ __launch_bounds__(256) void attn_combine(
    const float* __restrict__ qkv_a, const float* __restrict__ qkv_b,
    const float* __restrict__ part, float* __restrict__ out_k,
    float* __restrict__ out_v, float* __restrict__ attn) {
  const int t = threadIdx.x;
  const int h = blockIdx.x, b = blockIdx.y;
  const int bh = b * H_ + h;
  __shared__ float q_lds[NQ * 132];
  __shared__ float kn_lds[NQ * 132];
  __shared__ float vn_lds[NQ * 132];
  __shared__ float p9[NQ * 12];
  __shared__ float m9_lds[NQ], s9_lds[NQ];
  {
    int n = t >> 5, g = t & 31;
    const size_t soff = (size_t)(b * NQ + n) * F3 + h * D_ + g * 4;
    float4 qv = *reinterpret_cast<const float4*>(&qkv_a[soff]);
    float4 kv = *reinterpret_cast<const float4*>(&qkv_a[soff + E_]);
    float4 vv = *reinterpret_cast<const float4*>(&qkv_a[soff + 2 * E_]);
    if (qkv_b) {
      float4 q1 = *reinterpret_cast<const float4*>(&qkv_b[soff]);
      float4 k1 = *reinterpret_cast<const float4*>(&qkv_b[soff + E_]);
      float4 v1 = *reinterpret_cast<const float4*>(&qkv_b[soff + 2 * E_]);
      qv.x += q1.x; qv.y += q1.y; qv.z += q1.z; qv.w += q1.w;
      kv.x += k1.x; kv.y += k1.y; kv.z += k1.z; kv.w += k1.w;
      vv.x += v1.x; vv.y += v1.y; vv.z += v1.z; vv.w += v1.w;
    }
    *reinterpret_cast<float4*>(&q_lds[n * 132 + g * 4]) = qv;
    *reinterpret_cast<float4*>(&kn_lds[n * 132 + g * 4]) = kv;
    *reinterpret_cast<float4*>(&vn_lds[n * 132 + g * 4]) = vv;
    *reinterpret_cast<float4*>(&out_k[((size_t)bh * KVT + KVP + n) * D_ + g * 4]) = kv;
    *reinterpret_cast<float4*>(&out_v[((size_t)bh * KVT + KVP + n) * D_ + g * 4]) = vv;
  }
  __syncthreads();
  if (t < 64) {
    int nq = t >> 3, nk = t & 7;
    float s = 0.f;
#pragma unroll
    for (int g = 0; g < 32; ++g) {
      float4 qv = *reinterpret_cast<const float4*>(&q_lds[nq * 132 + g * 4]);
      float4 kv = *reinterpret_cast<const float4*>(&kn_lds[nk * 132 + g * 4]);
      s += qv.x * kv.x + qv.y * kv.y + qv.z * kv.z + qv.w * kv.w;
    }
    s *= SCALE;
    float mx = s;
#pragma unroll
    for (int o = 4; o > 0; o >>= 1) mx = fmaxf(mx, __shfl_xor(mx, o));
    float p = __expf(s - mx);
    float sm = p;
#pragma unroll
    for (int o = 4; o > 0; o >>= 1) sm += __shfl_xor(sm, o);
    p9[nk * 12 + nq] = p;
    if (nk == 0) { m9_lds[nq] = mx; s9_lds[nq] = sm; }
  }
  __syncthreads();
  const int qg = t >> 7, dcol = t & 127;
  const float* pb = part + (size_t)bh * NCHUNK * PARTSZ;
#pragma unroll
  for (int jq = 0; jq < 4; ++jq) {
    int qi = qg * 4 + jq;
    float M = m9_lds[qi];
#pragma unroll
    for (int c = 0; c < NCHUNK; ++c) M = fmaxf(M, pb[(size_t)c * PARTSZ + qi]);
    float num = 0.f, den = 0.f;
#pragma unroll
    for (int c = 0; c < NCHUNK; ++c) {
      const float* pc = pb + (size_t)c * PARTSZ;
      float wgt = __expf(pc[qi] - M);
      den += wgt * pc[8 + qi];
      num += wgt * pc[16 + (size_t)qi * D_ + dcol];
    }
    float acc9 = 0.f;
#pragma unroll
    for (int r = 0; r < NQ; ++r) acc9 += p9[r * 12 + qi] * vn_lds[r * 132 + dcol];
    float w9 = __expf(m9_lds[qi] - M);
    num += w9 * acc9;
    den += w9 * s9_lds[qi];
    attn[((size_t)(b * NQ + qi)) * E_ + h * D_ + dcol] = num / den;
  }
}

extern "C" void kernel_launch(void* const* d_in, const int* in_sizes, int n_in,
                              void* d_out, int out_size, void* d_ws, size_t ws_size,
                              hipStream_t stream) {
  const float* x      = (const float*)d_in[0];
  const float* past_k = (const float*)d_in[1];
  const float* past_v = (const float*)d_in[2];
  const float* W_qkv  = (const float*)d_in[3];
  const float* W_out  = (const float*)d_in[4];

  float* out   = (float*)d_out;
  float* out_k = out + (size_t)B_ * NQ * E_;
  float* out_v = out_k + (size_t)B_ * H_ * KVT * D_;

  const size_t QKV_N  = (size_t)B_ * NQ * F3;               // 786432
  const size_t PART_N = (size_t)B_ * H_ * NCHUNK * PARTSZ;  // 2129920
  const size_t ATTN_N = (size_t)B_ * NQ * E_;               // 262144
  const size_t need2  = (2 * QKV_N + PART_N + 3 * ATTN_N) * sizeof(float);

  float* ws = (float*)d_ws;
  const bool split2 = ws_size >= need2;

  float* pq0  = ws;
  float* pq1  = split2 ? ws + QKV_N : nullptr;
  float* part = ws + (split2 ? 2 : 1) * QKV_N;
  float* attn = part + PART_N;
  float* po0  = attn + ATTN_N;

  if (split2) {
    // 1) QKV projection, split-K=2 into separate partial buffers (384 blocks)
    gemm_xwt<64, 64, 2><<<dim3(F3 / 64, 2, 2), 256, 0, stream>>>(x, W_qkv, pq0, E_, F3);
  } else {
    gemm_xwt<64, 64, 1><<<dim3(F3 / 64, 2), 256, 0, stream>>>(x, W_qkv, pq0, E_, F3);
  }
  // 2) fused KV-cache copy + flash partials
  attn_partial<<<dim3(NCHUNK, H_, B_), 256, 0, stream>>>(past_k, past_v, pq0, pq1,
                                                         out_k, out_v, part);
  // 3) new-token chunk + combine
  attn_combine<<<dim3(H_, B_), 256, 0, stream>>>(pq0, pq1, part, out_k, out_v, attn);
  // 4) output projection
  if (split2) {
    gemm_xwt<64, 64, 2><<<dim3(E_ / 64, 2, 2), 256, 0, stream>>>(attn, W_out, po0, E_, E_);
    add2<<<dim3(ATTN_N / 1024), 256, 0, stream>>>(po0, po0 + ATTN_N, out);
  } else {
    gemm_xwt<64, 64, 1><<<dim3(E_ / 64, 2), 256, 0, stream>>>(attn, W_out, out, E_, E_);
  }
}

// Round 7
// 565.458 us; speedup vs baseline: 1.4239x; 1.0044x over previous
//
#include <hip/hip_runtime.h>
#include <cstddef>
#include <cstdint>

#define B_ 16
#define H_ 16
#define NQ 8
#define D_ 128
#define E_ 2048
#define F3 6144
#define KVP 4096
#define KVT 4104
#define SCALE 0.08838834764831843f
#define NCHUNK 8
#define CHUNK 512
#define PARTSZ 1040  // 8 m + 8 l + 8*128 acc

// wave-local LDS ordering: no barrier, just drain DS ops of this wave
#define WAVE_LDS_FENCE() asm volatile("s_waitcnt lgkmcnt(0)" ::: "memory")

// ---------------- GEMM: C[M][F] = X[M][K] * W[F][K]^T (fp32) ----------------
// SPLITK>1: block z writes its partial to C + z*128*Fdim (separate buffers, no atomics).
template <int BM, int BN, int SPLITK>
__global__ __launch_bounds__(256) void gemm_xwt(const float* __restrict__ X,
                                                const float* __restrict__ W,
                                                float* __restrict__ C,
                                                int K, int Fdim) {
  constexpr int BK = 32;
  constexpr int RM = BM / 16;
  constexpr int RN = BN / 16;
  __shared__ float xs[BK][BM + 4];
  __shared__ float wss[BK][BN + 4];
  const int t = threadIdx.x;
  const int tm = t >> 4, tn = t & 15;
  const int m0 = blockIdx.y * BM, f0 = blockIdx.x * BN;
  const int kbeg = (SPLITK > 1) ? blockIdx.z * (K / SPLITK) : 0;
  const int kend = (SPLITK > 1) ? kbeg + K / SPLITK : K;
  if (SPLITK > 1) C += (size_t)blockIdx.z * 128 * Fdim;
  float acc[RM][RN];
#pragma unroll
  for (int i = 0; i < RM; ++i)
#pragma unroll
    for (int j = 0; j < RN; ++j) acc[i][j] = 0.f;

  for (int kk = kbeg; kk < kend; kk += BK) {
#pragma unroll
    for (int i = 0; i < (BM * BK) / 1024; ++i) {
      int j = t + i * 256;
      int r = j >> 3;
      int c = (j & 7) << 2;
      float4 v = *reinterpret_cast<const float4*>(&X[(size_t)(m0 + r) * K + kk + c]);
      xs[c + 0][r] = v.x; xs[c + 1][r] = v.y; xs[c + 2][r] = v.z; xs[c + 3][r] = v.w;
    }
#pragma unroll
    for (int i = 0; i < (BN * BK) / 1024; ++i) {
      int j = t + i * 256;
      int r = j >> 3;
      int c = (j & 7) << 2;
      float4 v = *reinterpret_cast<const float4*>(&W[(size_t)(f0 + r) * K + kk + c]);
      wss[c + 0][r] = v.x; wss[c + 1][r] = v.y; wss[c + 2][r] = v.z; wss[c + 3][r] = v.w;
    }
    __syncthreads();
#pragma unroll
    for (int k = 0; k < BK; ++k) {
      float xv[RM], wv[RN];
      if constexpr (RM == 4) {
        *reinterpret_cast<float4*>(xv) = *reinterpret_cast<const float4*>(&xs[k][tm * 4]);
      } else {
        *reinterpret_cast<float2*>(xv) = *reinterpret_cast<const float2*>(&xs[k][tm * 2]);
      }
      if constexpr (RN == 4) {
        *reinterpret_cast<float4*>(wv) = *reinterpret_cast<const float4*>(&wss[k][tn * 4]);
      } else {
        *reinterpret_cast<float2*>(wv) = *reinterpret_cast<const float2*>(&wss[k][tn * 2]);
      }
#pragma unroll
      for (int i = 0; i < RM; ++i)
#pragma unroll
        for (int j = 0; j < RN; ++j) acc[i][j] += xv[i] * wv[j];
    }
    __syncthreads();
  }
#pragma unroll
  for (int i = 0; i < RM; ++i) {
    float* cp = &C[(size_t)(m0 + tm * RM + i) * Fdim + f0 + tn * RN];
    if constexpr (RN == 4) {
      *reinterpret_cast<float4*>(cp) = make_float4(acc[i][0], acc[i][1], acc[i][2], acc[i][3]);
    } else {
      *reinterpret_cast<float2*>(cp) = make_float2(acc[i][0], acc[i][1]);
    }
  }
}

// o = a + b, n4 float4s, grid*block == n4
__global__ __launch_bounds__(256) void add2(const float* __restrict__ a,
                                            const float* __restrict__ b,
                                            float* __restrict__ o) {
  int i = blockIdx.x * 256 + threadIdx.x;
  float4 va = reinterpret_cast<const float4*>(a)[i];
  float4 vb = reinterpret_cast<const float4*>(b)[i];
  reinterpret_cast<float4*>(o)[i] =
      make_float4(va.x + vb.x, va.y + vb.y, va.z + vb.z, va.w + vb.w);
}

// ------- Fused KV-cache copy + flash-attention partials over past chunks -------
// grid: (NCHUNK, H, B), 256 threads = 4 waves. Each WAVE independently processes a
// private 128-row slice with its own online softmax state — ZERO barriers in the
// main loop (wave-local LDS scratch + lgkmcnt fences only). Waves merge once at end.
// Lane l: col g = l&31 (f4), half = l>>5; per 8-row group lane owns rows half+2j.
__global__ __launch_bounds__(256) void attn_partial(
    const float* __restrict__ past_k, const float* __restrict__ past_v,
    const float* __restrict__ qkv_a, const float* __restrict__ qkv_b,
    float* __restrict__ out_k, float* __restrict__ out_v,
    float* __restrict__ part) {
  const int t = threadIdx.x;
  const int c = blockIdx.x, h = blockIdx.y, b = blockIdx.z;
  const int bh = b * H_ + h;
  const int l = t & 63, w = t >> 6;
  const int g = l & 31, half = l >> 5;

  __shared__ float red[4096];          // 16KB end-merge buffer [w][qi][128]
  __shared__ float scratch[4][160];    // per-wave: s(72) | p(64 @72) | f(8 @136)
  __shared__ float mw_lds[32], lw_lds[32];
  float* s_w = scratch[w];
  float* p_w = scratch[w] + 72;
  float* f_w = scratch[w] + 136;

  // Q resident in registers (sum of split-K partials): fixed f4-column g, all 8 q-rows
  float4 qreg[NQ];
#pragma unroll
  for (int qi = 0; qi < NQ; ++qi) {
    const size_t qoff = (size_t)(b * NQ + qi) * F3 + h * D_ + g * 4;
    float4 q0 = *reinterpret_cast<const float4*>(&qkv_a[qoff]);
    if (qkv_b) {
      float4 q1 = *reinterpret_cast<const float4*>(&qkv_b[qoff]);
      q0.x += q1.x; q0.y += q1.y; q0.z += q1.z; q0.w += q1.w;
    }
    qreg[qi] = q0;
  }

  // wave slice base (chunk-relative row)
  const int wbase = w * 128;
  const float* gk = past_k + ((size_t)bh * KVP + (size_t)c * CHUNK) * D_;
  const float* gv = past_v + ((size_t)bh * KVP + (size_t)c * CHUNK) * D_;
  float* ok = out_k + ((size_t)bh * KVT + (size_t)c * CHUNK) * D_;
  float* ov = out_v + ((size_t)bh * KVT + (size_t)c * CHUNK) * D_;

  float4 acc[NQ];
#pragma unroll
  for (int qi = 0; qi < NQ; ++qi) acc[qi] = make_float4(0.f, 0.f, 0.f, 0.f);
  float m_run = -1e30f, l_run = 0.f;  // this lane's qi-group state (qi = l>>3)

  const int b0 = g & 1, b1 = (g >> 1) & 1, b2 = (g >> 2) & 1;
  const int qsel = 4 * b0 + 2 * b1 + b2;
  const int srow = l & 7, sqi = l >> 3;  // softmax-phase role

  auto loadf = [&](float4 (&kf)[4], float4 (&vf)[4], int it) {
#pragma unroll
    for (int j = 0; j < 4; ++j) {
      const size_t ga = (size_t)(wbase + it * 8 + half + 2 * j) * D_ + g * 4;
      kf[j] = *reinterpret_cast<const float4*>(&gk[ga]);
      vf[j] = *reinterpret_cast<const float4*>(&gv[ga]);
    }
  };

  auto bodyf = [&](float4 (&kf)[4], float4 (&vf)[4], int it) {
    // ---- scores + copy-through (plain stores) ----
#pragma unroll
    for (int j = 0; j < 4; ++j) {
      const int r = half + 2 * j;
      const size_t ga = (size_t)(wbase + it * 8 + r) * D_ + g * 4;
      *reinterpret_cast<float4*>(&ok[ga]) = kf[j];
      *reinterpret_cast<float4*>(&ov[ga]) = vf[j];
      float sp[NQ];
#pragma unroll
      for (int qi = 0; qi < NQ; ++qi)
        sp[qi] = kf[j].x * qreg[qi].x + kf[j].y * qreg[qi].y +
                 kf[j].z * qreg[qi].z + kf[j].w * qreg[qi].w;
      // butterfly: 8 vals -> 1 per lane over this 32-lane half (row r)
      float v1[4];
#pragma unroll
      for (int jj = 0; jj < 4; ++jj) {
        float x = b0 ? sp[jj] : sp[jj + 4];
        v1[jj] = (b0 ? sp[jj + 4] : sp[jj]) + __shfl_xor(x, 1);
      }
      float v2[2];
#pragma unroll
      for (int jj = 0; jj < 2; ++jj) {
        float x = b1 ? v1[jj] : v1[jj + 2];
        v2[jj] = (b1 ? v1[jj + 2] : v1[jj]) + __shfl_xor(x, 2);
      }
      float v3;
      {
        float x = b2 ? v2[0] : v2[1];
        v3 = (b2 ? v2[1] : v2[0]) + __shfl_xor(x, 4);
      }
      v3 += __shfl_xor(v3, 8);
      v3 += __shfl_xor(v3, 16);
      if (g < 8) s_w[r * 9 + qsel] = v3;
    }
    WAVE_LDS_FENCE();  // s_w visible wave-wide

    // ---- wave-local online softmax (lane role: row=srow, qi=sqi) ----
    {
      float s = s_w[srow * 9 + sqi] * SCALE;
      float cmax = s;
      cmax = fmaxf(cmax, __shfl_xor(cmax, 1));
      cmax = fmaxf(cmax, __shfl_xor(cmax, 2));
      cmax = fmaxf(cmax, __shfl_xor(cmax, 4));
      float mn = fmaxf(m_run, cmax);
      float p = __expf(s - mn);
      float ps = p;
      ps += __shfl_xor(ps, 1);
      ps += __shfl_xor(ps, 2);
      ps += __shfl_xor(ps, 4);
      float f = __expf(m_run - mn);
      p_w[srow * 8 + sqi] = p;
      if (srow == 0) f_w[sqi] = f;
      l_run = l_run * f + ps;
      m_run = mn;
    }
    WAVE_LDS_FENCE();  // p_w/f_w visible wave-wide

    // ---- PV on register V rows ----
    {
      float4 f0 = *reinterpret_cast<const float4*>(&f_w[0]);
      float4 f1 = *reinterpret_cast<const float4*>(&f_w[4]);
      acc[0].x *= f0.x; acc[0].y *= f0.x; acc[0].z *= f0.x; acc[0].w *= f0.x;
      acc[1].x *= f0.y; acc[1].y *= f0.y; acc[1].z *= f0.y; acc[1].w *= f0.y;
      acc[2].x *= f0.z; acc[2].y *= f0.z; acc[2].z *= f0.z; acc[2].w *= f0.z;
      acc[3].x *= f0.w; acc[3].y *= f0.w; acc[3].z *= f0.w; acc[3].w *= f0.w;
      acc[4].x *= f1.x; acc[4].y *= f1.x; acc[4].z *= f1.x; acc[4].w *= f1.x;
      acc[5].x *= f1.y; acc[5].y *= f1.y; acc[5].z *= f1.y; acc[5].w *= f1.y;
      acc[6].x *= f1.z; acc[6].y *= f1.z; acc[6].z *= f1.z; acc[6].w *= f1.z;
      acc[7].x *= f1.w; acc[7].y *= f1.w; acc[7].z *= f1.w; acc[7].w *= f1.w;
#pragma unroll
      for (int j = 0; j < 4; ++j) {
        const int r = half + 2 * j;
        float4 pa = *reinterpret_cast<const float4*>(&p_w[r * 8]);      // broadcast
        float4 pc = *reinterpret_cast<const float4*>(&p_w[r * 8 + 4]);  // broadcast
        acc[0].x += pa.x * vf[j].x; acc[0].y += pa.x * vf[j].y; acc[0].z += pa.x * vf[j].z; acc[0].w += pa.x * vf[j].w;
        acc[1].x += pa.y * vf[j].x; acc[1].y += pa.y * vf[j].y; acc[1].z += pa.y * vf[j].z; acc[1].w += pa.y * vf[j].w;
        acc[2].x += pa.z * vf[j].x; acc[2].y += pa.z * vf[j].y; acc[2].z += pa.z * vf[j].z; acc[2].w += pa.z * vf[j].w;
        acc[3].x += pa.w * vf[j].x; acc[3].y += pa.w * vf[j].y; acc[3].z += pa.w * vf[j].z; acc[3].w += pa.w * vf[j].w;
        acc[4].x += pc.x * vf[j].x; acc[4].y += pc.x * vf[j].y; acc[4].z += pc.x * vf[j].z; acc[4].w += pc.x * vf[j].w;
        acc[5].x += pc.y * vf[j].x; acc[5].y += pc.y * vf[j].y; acc[5].z += pc.y * vf[j].z; acc[5].w += pc.y * vf[j].w;
        acc[6].x += pc.z * vf[j].x; acc[6].y += pc.z * vf[j].y; acc[6].z += pc.z * vf[j].z; acc[6].w += pc.z * vf[j].w;
        acc[7].x += pc.w * vf[j].x; acc[7].y += pc.w * vf[j].y; acc[7].z += pc.w * vf[j].z; acc[7].w += pc.w * vf[j].w;
      }
    }
  };

  float4 kA[4], vA[4], kB[4], vB[4];
  loadf(kA, vA, 0);
  for (int it = 0; it < 16; it += 2) {
    if (it + 1 < 16) loadf(kB, vB, it + 1);  // prefetch, hidden under body
    bodyf(kA, vA, it);
    if (it + 2 < 16) loadf(kA, vA, it + 2);
    bodyf(kB, vB, it + 1);
  }

  // ---- combine the two halves' row-parity partials (same column g) ----
#pragma unroll
  for (int qi = 0; qi < NQ; ++qi) {
    acc[qi].x += __shfl_xor(acc[qi].x, 32);
    acc[qi].y += __shfl_xor(acc[qi].y, 32);
    acc[qi].z += __shfl_xor(acc[qi].z, 32);
    acc[qi].w += __shfl_xor(acc[qi].w, 32);
  }

  // ---- publish wave partials, single block barrier, merge 4 waves ----
  if (srow == 0) { mw_lds[w * 8 + sqi] = m_run; lw_lds[w * 8 + sqi] = l_run; }
  if (half == 0) {
#pragma unroll
    for (int qi = 0; qi < NQ; ++qi)
      *reinterpret_cast<float4*>(&red[w * 1024 + qi * 128 + g * 4]) = acc[qi];
  }
  __syncthreads();

  {
    const int col4 = t & 31, qi = (t >> 5) & 7;
    float M = mw_lds[qi];
    M = fmaxf(M, mw_lds[8 + qi]);
    M = fmaxf(M, mw_lds[16 + qi]);
    M = fmaxf(M, mw_lds[24 + qi]);
    float den = 0.f;
    float4 num = make_float4(0.f, 0.f, 0.f, 0.f);
#pragma unroll
    for (int ww = 0; ww < 4; ++ww) {
      float wt = __expf(mw_lds[ww * 8 + qi] - M);
      den += wt * lw_lds[ww * 8 + qi];
      float4 a = *reinterpret_cast<const float4*>(&red[ww * 1024 + qi * 128 + col4 * 4]);
      num.x += wt * a.x; num.y += wt * a.y; num.z += wt * a.z; num.w += wt * a.w;
    }
    float* pb = part + ((size_t)bh * NCHUNK + c) * PARTSZ;
    *reinterpret_cast<float4*>(&pb[16 + qi * 128 + col4 * 4]) = num;
    if (col4 == 0) { pb[qi] = M; pb[8 + qi] = den; }
  }
}

// ------- new-token chunk + combine partials -> attention output (pre-proj) -------
// grid: (H, B), 256 threads.
__global__ __launch_bounds__(256) void attn_combine(
    const float* __restrict__ qkv_a, const float* __restrict__ qkv_b,
    const float* __restrict__ part, float* __restrict__ out_k,
    float* __restrict__ out_v, float* __restrict__ attn) {
  const int t = threadIdx.x;
  const int h = blockIdx.x, b = blockIdx.y;
  const int bh = b * H_ + h;
  __shared__ float q_lds[NQ * 132];
  __shared__ float kn_lds[NQ * 132];
  __shared__ float vn_lds[NQ * 132];
  __shared__ float p9[NQ * 12];
  __shared__ float m9_lds[NQ], s9_lds[NQ];
  {
    int n = t >> 5, g = t & 31;
    const size_t soff = (size_t)(b * NQ + n) * F3 + h * D_ + g * 4;
    float4 qv = *reinterpret_cast<const float4*>(&qkv_a[soff]);
    float4 kv = *reinterpret_cast<const float4*>(&qkv_a[soff + E_]);
    float4 vv = *reinterpret_cast<const float4*>(&qkv_a[soff + 2 * E_]);
    if (qkv_b) {
      float4 q1 = *reinterpret_cast<const float4*>(&qkv_b[soff]);
      float4 k1 = *reinterpret_cast<const float4*>(&qkv_b[soff + E_]);
      float4 v1 = *reinterpret_cast<const float4*>(&qkv_b[soff + 2 * E_]);
      qv.x += q1.x; qv.y += q1.y; qv.z += q1.z; qv.w += q1.w;
      kv.x += k1.x; kv.y += k1.y; kv.z += k1.z; kv.w += k1.w;
      vv.x += v1.x; vv.y += v1.y; vv.z += v1.z; vv.w += v1.w;
    }
    *reinterpret_cast<float4*>(&q_lds[n * 132 + g * 4]) = qv;
    *reinterpret_cast<float4*>(&kn_lds[n * 132 + g * 4]) = kv;
    *reinterpret_cast<float4*>(&vn_lds[n * 132 + g * 4]) = vv;
    *reinterpret_cast<float4*>(&out_k[((size_t)bh * KVT + KVP + n) * D_ + g * 4]) = kv;
    *reinterpret_cast<float4*>(&out_v[((size_t)bh * KVT + KVP + n) * D_ + g * 4]) = vv;
  }
  __syncthreads();
  if (t < 64) {
    int nq = t >> 3, nk = t & 7;
    float s = 0.f;
#pragma unroll
    for (int g = 0; g < 32; ++g) {
      float4 qv = *reinterpret_cast<const float4*>(&q_lds[nq * 132 + g * 4]);
      float4 kv = *reinterpret_cast<const float4*>(&kn_lds[nk * 132 + g * 4]);
      s += qv.x * kv.x + qv.y * kv.y + qv.z * kv.z + qv.w * kv.w;
    }
    s *= SCALE;
    float mx = s;
#pragma unroll
    for (int o = 4; o > 0; o >>= 1) mx = fmaxf(mx, __shfl_xor(mx, o));
    float p = __expf(s - mx);
    float sm = p;
#pragma unroll
    for (int o = 4; o > 0; o >>= 1) sm += __shfl_xor(sm, o);
    p9[nk * 12 + nq] = p;
    if (nk == 0) { m9_lds[nq] = mx; s9_lds[nq] = sm; }
  }
  __syncthreads();
  const int qg = t >> 7, dcol = t & 127;
  const float* pb = part + (size_t)bh * NCHUNK * PARTSZ;
#pragma unroll
  for (int jq = 0; jq < 4; ++jq) {
    int qi = qg * 4 + jq;
    float M = m9_lds[qi];
#pragma unroll
    for (int c = 0; c < NCHUNK; ++c) M = fmaxf(M, pb[(size_t)c * PARTSZ + qi]);
    float num = 0.f, den = 0.f;
#pragma unroll
    for (int c = 0; c < NCHUNK; ++c) {
      const float* pc = pb + (size_t)c * PARTSZ;
      float wgt = __expf(pc[qi] - M);
      den += wgt * pc[8 + qi];
      num += wgt * pc[16 + (size_t)qi * D_ + dcol];
    }
    float acc9 = 0.f;
#pragma unroll
    for (int r = 0; r < NQ; ++r) acc9 += p9[r * 12 + qi] * vn_lds[r * 132 + dcol];
    float w9 = __expf(m9_lds[qi] - M);
    num += w9 * acc9;
    den += w9 * s9_lds[qi];
    attn[((size_t)(b * NQ + qi)) * E_ + h * D_ + dcol] = num / den;
  }
}

extern "C" void kernel_launch(void* const* d_in, const int* in_sizes, int n_in,
                              void* d_out, int out_size, void* d_ws, size_t ws_size,
                              hipStream_t stream) {
  const float* x      = (const float*)d_in[0];
  const float* past_k = (const float*)d_in[1];
  const float* past_v = (const float*)d_in[2];
  const float* W_qkv  = (const float*)d_in[3];
  const float* W_out  = (const float*)d_in[4];

  float* out   = (float*)d_out;
  float* out_k = out + (size_t)B_ * NQ * E_;
  float* out_v = out_k + (size_t)B_ * H_ * KVT * D_;

  const size_t QKV_N  = (size_t)B_ * NQ * F3;               // 786432
  const size_t PART_N = (size_t)B_ * H_ * NCHUNK * PARTSZ;  // 2129920
  const size_t ATTN_N = (size_t)B_ * NQ * E_;               // 262144
  const size_t need2  = (2 * QKV_N + PART_N + 3 * ATTN_N) * sizeof(float);

  float* ws = (float*)d_ws;
  const bool split2 = ws_size >= need2;

  float* pq0  = ws;
  float* pq1  = split2 ? ws + QKV_N : nullptr;
  float* part = ws + (split2 ? 2 : 1) * QKV_N;
  float* attn = part + PART_N;
  float* po0  = attn + ATTN_N;

  if (split2) {
    gemm_xwt<64, 64, 2><<<dim3(F3 / 64, 2, 2), 256, 0, stream>>>(x, W_qkv, pq0, E_, F3);
  } else {
    gemm_xwt<64, 64, 1><<<dim3(F3 / 64, 2), 256, 0, stream>>>(x, W_qkv, pq0, E_, F3);
  }
  attn_partial<<<dim3(NCHUNK, H_, B_), 256, 0, stream>>>(past_k, past_v, pq0, pq1,
                                                         out_k, out_v, part);
  attn_combine<<<dim3(H_, B_), 256, 0, stream>>>(pq0, pq1, part, out_k, out_v, attn);
  if (split2) {
    gemm_xwt<64, 64, 2><<<dim3(E_ / 64, 2, 2), 256, 0, stream>>>(attn, W_out, po0, E_, E_);
    add2<<<dim3(ATTN_N / 1024), 256, 0, stream>>>(po0, po0 + ATTN_N, out);
  } else {
    gemm_xwt<64, 64, 1><<<dim3(E_ / 64, 2), 256, 0, stream>>>(attn, W_out, out, E_, E_);
  }
}